// Round 9
// baseline (1021.982 us; speedup 1.0000x reference)
//
#include <hip/hip_runtime.h>
#include <hip/hip_bf16.h>

// RQV residual VQ — MFMA dist (B-lo direct from L2, B-hi LDS-staged) + prefetched update.
// Inputs (fp32): data [16,256,2048], codebooks [8,1024,256], N_i [8,1024], m_i [8,1024,256]
// Outputs (fp32 concat): logits, loss, indices, new_N, new_m, new_W
// ws: 43,122,688 B (same layout as r8)

using f16   = _Float16;
using f16x4 = __attribute__((ext_vector_type(4))) _Float16;
using f16x8 = __attribute__((ext_vector_type(8))) _Float16;
using f32x4 = __attribute__((ext_vector_type(4))) float;

#define GAMMA_F 0.99f
#define OMG_F   0.01f
#define LO_SCALE 1024.0f
#define LO_INV   (1.0f/1024.0f)

__global__ void sentinel_kernel(float* out, float v){
  if (threadIdx.x == 0 && blockIdx.x == 0) out[0] = v;
}

// ---------- codebook row norms ----------
__global__ __launch_bounds__(64) void rownorm_kernel(const float* __restrict__ X,
                                                     float* __restrict__ out, int rows){
  int r = blockIdx.x;
  if (r >= rows) return;
  int l = threadIdx.x;
  const float* x = X + (size_t)r * 256;
  float s = 0.f;
  #pragma unroll
  for (int i = 0; i < 4; i++){ float v = x[l + i*64]; s += v*v; }
  #pragma unroll
  for (int o = 32; o > 0; o >>= 1) s += __shfl_down(s, o, 64);
  if (l == 0) out[r] = s;
}

// ---------- codebook split into MFMA B-fragment order (verified) ----------
__global__ __launch_bounds__(64) void wsplit_kernel(const float* __restrict__ W,
                                                    f16* __restrict__ frag){
  int blk = blockIdx.x;                 // (q*64+ct)*8+kf
  int lane = threadIdx.x;
  int code = (blk >> 3 << 4) + (lane & 15);
  int k0   = (blk & 7)*32 + (lane >> 4)*8;
  const float* src = W + (size_t)code * 256 + k0;
  float4 a = *(const float4*)(src);
  float4 b = *(const float4*)(src + 4);
  float x[8] = {a.x,a.y,a.z,a.w, b.x,b.y,b.z,b.w};
  f16x8 h8, l8;
  #pragma unroll
  for (int i = 0; i < 8; i++){
    f16 h = (f16)x[i];
    h8[i] = h;
    l8[i] = (f16)((x[i] - (float)h) * LO_SCALE);
  }
  f16* dst = frag + (size_t)blk * 1024 + lane*8;
  *(f16x8*)dst         = h8;
  *(f16x8*)(dst + 512) = l8;
}

// ---------- init: data -> ROW-MAJOR fp16 hi/lo planes + rownorm ----------
__global__ __launch_bounds__(256) void init_kernel(const float* __restrict__ data,
                                                   f16* __restrict__ AH, f16* __restrict__ AL,
                                                   float* __restrict__ rnorm){
  __shared__ float rs[32][257];
  __shared__ float nrmp[32][8];
  int blk = blockIdx.x, b = blk >> 6, s0 = (blk & 63) * 32;
  int tid = threadIdx.x, c = tid & 31, g = tid >> 5;
  const float* dptr = data + (size_t)b * 524288 + s0;
  float np_ = 0.f;
  #pragma unroll 8
  for (int dd = 0; dd < 32; ++dd){
    int d = g*32 + dd;
    float x = dptr[(size_t)d * 2048 + c];
    rs[c][d] = x;
    np_ += x*x;
  }
  nrmp[c][g] = np_;
  __syncthreads();
  if (tid < 32){
    float s = 0.f;
    #pragma unroll
    for (int gg = 0; gg < 8; ++gg) s += nrmp[tid][gg];
    rnorm[blk*32 + tid] = s;
  }
  int r0 = blk*32;
  int c2 = tid >> 3, k0 = (tid & 7) * 32;
  #pragma unroll
  for (int jc = 0; jc < 4; ++jc){
    f16x8 h8, l8;
    #pragma unroll
    for (int j = 0; j < 8; ++j){
      float x = rs[c2][k0 + jc*8 + j];
      f16 h = (f16)x;
      h8[j] = h;
      l8[j] = (f16)((x - (float)h) * LO_SCALE);
    }
    size_t off = (size_t)(r0 + c2) * 256 + k0 + jc*8;
    *(f16x8*)(AH + off) = h8;
    *(f16x8*)(AL + off) = l8;
  }
}

// ---------- out4 = mi * gamma ----------
__global__ __launch_bounds__(256) void out4init_kernel(const float* __restrict__ mi,
                                                       float* __restrict__ out4){
  int e4 = blockIdx.x*256 + threadIdx.x;
  float4 v = ((const float4*)mi)[e4];
  v.x *= GAMMA_F; v.y *= GAMMA_F; v.z *= GAMMA_F; v.w *= GAMMA_F;
  ((float4*)out4)[e4] = v;
}

// ---------- dist: B-hi LDS double-buffered, B-lo direct from global ----------
__global__ __launch_bounds__(256, 2) void dist_kernel(
    const f16* __restrict__ AH, const f16* __restrict__ AL,
    const f16* __restrict__ whl, const float* __restrict__ wnorm,
    const float* __restrict__ rnorm, float* __restrict__ pv,
    unsigned short* __restrict__ pi, int q)
{
  __shared__ f16 Bs[2][4096];          // bh only: 8 KB per buffer
  const int tid = threadIdx.x;
  const int lane = tid & 63;
  const int w = tid >> 6;
  const int rb = blockIdx.x, cs = blockIdx.y;
  const int rlo = lane & 15, kg = lane >> 4;
  const int T0 = rb*8 + w*2;

  // A fragments from row-major planes (hi/lo, 32 rows)
  f16x8 aH[2][8], aL[2][8];
  #pragma unroll
  for (int rt = 0; rt < 2; ++rt)
    #pragma unroll
    for (int kf = 0; kf < 8; ++kf){
      size_t off = (size_t)((T0+rt)*16 + rlo) * 256 + kf*32 + kg*8;
      aH[rt][kf] = *(const f16x8*)(AH + off);
      aL[rt][kf] = *(const f16x8*)(AL + off);
    }
  float rn[2][4];
  #pragma unroll
  for (int rt = 0; rt < 2; ++rt)
    #pragma unroll
    for (int i = 0; i < 4; ++i)
      rn[rt][i] = rnorm[(T0+rt)*16 + kg*4 + i];

  const f16* wb = whl + (size_t)q * 524288;
  const float* wn = wnorm + (q << 10);
  const int ct0 = cs * 16;

  float bestv[8]; int besti[8];
  #pragma unroll
  for (int r8 = 0; r8 < 8; ++r8){ bestv[r8] = 3.4e38f; besti[r8] = 0; }

  // prologue: stage bh of it=0 (wave w covers kf = 2w, 2w+1)
  {
    const f16* src = wb + (size_t)ct0*8192 + (w*2)*1024 + lane*8;
    f16x8 s0 = *(const f16x8*)(src);
    f16x8 s1 = *(const f16x8*)(src + 1024);
    f16* dst = &Bs[0][0] + (w*2)*512 + lane*8;
    *(f16x8*)dst         = s0;
    *(f16x8*)(dst + 512) = s1;
  }

  for (int it = 0; it < 16; ++it){
    int ct = ct0 + it;
    __syncthreads();                    // Bs[it&1] ready for all waves
    // prefetch next bh tile into regs (staged after compute)
    f16x8 nx0, nx1;
    if (it < 15){
      const f16* src = wb + (size_t)(ct+1)*8192 + (w*2)*1024 + lane*8;
      nx0 = *(const f16x8*)(src);
      nx1 = *(const f16x8*)(src + 1024);
    }
    // bl for this tile: direct from global (L2-resident), bypasses LDS
    f16x8 blr[8];
    {
      const f16* bls = wb + (size_t)ct*8192 + 512 + lane*8;
      #pragma unroll
      for (int kf = 0; kf < 8; ++kf) blr[kf] = *(const f16x8*)(bls + kf*1024);
    }
    const f16* bb = &Bs[it & 1][0];
    f32x4 hh[2], cr[2];
    #pragma unroll
    for (int rt = 0; rt < 2; ++rt){ hh[rt] = (f32x4)0.0f; cr[rt] = (f32x4)0.0f; }
    #pragma unroll
    for (int kf = 0; kf < 8; ++kf){
      f16x8 bh = *(const f16x8*)(bb + kf*512 + lane*8);
      hh[0] = __builtin_amdgcn_mfma_f32_16x16x32_f16(aH[0][kf], bh,      hh[0], 0,0,0);
      cr[0] = __builtin_amdgcn_mfma_f32_16x16x32_f16(aH[0][kf], blr[kf], cr[0], 0,0,0);
      cr[0] = __builtin_amdgcn_mfma_f32_16x16x32_f16(aL[0][kf], bh,      cr[0], 0,0,0);
      hh[1] = __builtin_amdgcn_mfma_f32_16x16x32_f16(aH[1][kf], bh,      hh[1], 0,0,0);
      cr[1] = __builtin_amdgcn_mfma_f32_16x16x32_f16(aH[1][kf], blr[kf], cr[1], 0,0,0);
      cr[1] = __builtin_amdgcn_mfma_f32_16x16x32_f16(aL[1][kf], bh,      cr[1], 0,0,0);
    }
    {
      int code = (ct << 4) + rlo;
      float wnc = wn[code];
      #pragma unroll
      for (int rt = 0; rt < 2; ++rt)
        #pragma unroll
        for (int i = 0; i < 4; ++i){
          float dot = hh[rt][i] + cr[rt][i] * LO_INV;
          float d2 = (rn[rt][i] + wnc) - 2.0f * dot;
          int r8 = rt*4 + i;
          if (d2 < bestv[r8] || (d2 == bestv[r8] && code < besti[r8])){
            bestv[r8] = d2; besti[r8] = code;
          }
        }
    }
    if (it < 15){
      f16* dst = &Bs[(it+1) & 1][0] + (w*2)*512 + lane*8;
      *(f16x8*)dst         = nx0;
      *(f16x8*)(dst + 512) = nx1;
    }
  }

  #pragma unroll
  for (int off = 1; off <= 8; off <<= 1){
    #pragma unroll
    for (int r8 = 0; r8 < 8; ++r8){
      float ov = __shfl_xor(bestv[r8], off, 16);
      int   oi = __shfl_xor(besti[r8], off, 16);
      if (ov < bestv[r8] || (ov == bestv[r8] && oi < besti[r8])){
        bestv[r8] = ov; besti[r8] = oi;
      }
    }
  }
  if (rlo == 0){
    #pragma unroll
    for (int r8 = 0; r8 < 8; ++r8){
      int rt = r8 >> 2, i = r8 & 3;
      int grow = (T0 + rt)*16 + kg*4 + i;
      pv[cs*32768 + grow] = bestv[r8];
      pi[cs*32768 + grow] = (unsigned short)besti[r8];
    }
  }
}

// ---------- combine partials + per-block histogram ----------
__global__ __launch_bounds__(256) void combine_kernel(
    const float* __restrict__ pv, const unsigned short* __restrict__ pi,
    float* __restrict__ out2q, unsigned short* __restrict__ blockhist){
  __shared__ int h[1024];
  int tid = threadIdx.x, b = blockIdx.x;
  #pragma unroll
  for (int i = 0; i < 4; ++i) h[tid + 256*i] = 0;
  __syncthreads();
  #pragma unroll
  for (int j = 0; j < 4; ++j){
    int row = b*1024 + tid + 256*j;
    float bv = pv[row]; int bi = pi[row];
    #pragma unroll
    for (int cs = 1; cs < 4; ++cs){
      float v = pv[cs*32768 + row];
      int  ii = pi[cs*32768 + row];
      if (v < bv){ bv = v; bi = ii; }     // strict <: ties keep lower cs = lower code
    }
    out2q[row] = (float)bi;
    atomicAdd(&h[bi], 1);
  }
  __syncthreads();
  #pragma unroll
  for (int i = 0; i < 4; ++i)
    blockhist[b*1024 + tid + 256*i] = (unsigned short)h[tid + 256*i];
}

// ---------- scan -> per-block starts (in place) + new_N ----------
__global__ __launch_bounds__(256) void scan_kernel(unsigned short* __restrict__ blockhist,
                                                   const float* __restrict__ Ni,
                                                   float* __restrict__ out3, int q){
  __shared__ int wtot[4];
  int tid = threadIdx.x, lane = tid & 63, w = tid >> 6;
  ushort4* bh4 = (ushort4*)blockhist;
  int tx=0, ty=0, tz=0, tw=0;
  for (int b = 0; b < 32; ++b){
    ushort4 h = bh4[b*256 + tid];
    tx += h.x; ty += h.y; tz += h.z; tw += h.w;
  }
  int s = tx + ty + tz + tw;
  int v = s;
  #pragma unroll
  for (int d = 1; d < 64; d <<= 1){
    int o = __shfl_up(v, d, 64);
    if (lane >= d) v += o;
  }
  if (lane == 63) wtot[w] = v;
  __syncthreads();
  int woff = 0;
  #pragma unroll
  for (int ww = 0; ww < 4; ++ww) if (ww < w) woff += wtot[ww];
  int base = woff + v - s;
  const int qb = q << 10;
  out3[qb + tid*4+0] = Ni[qb + tid*4+0]*GAMMA_F + (float)tx*OMG_F;
  out3[qb + tid*4+1] = Ni[qb + tid*4+1]*GAMMA_F + (float)ty*OMG_F;
  out3[qb + tid*4+2] = Ni[qb + tid*4+2]*GAMMA_F + (float)tz*OMG_F;
  out3[qb + tid*4+3] = Ni[qb + tid*4+3]*GAMMA_F + (float)tw*OMG_F;
  int r0 = base, r1 = base + tx, r2 = r1 + ty, r3 = r2 + tz;
  for (int b = 0; b < 32; ++b){
    ushort4 h = bh4[b*256 + tid];
    ushort4 st; st.x = (unsigned short)r0; st.y = (unsigned short)r1;
    st.z = (unsigned short)r2; st.w = (unsigned short)r3;
    bh4[b*256 + tid] = st;
    r0 += h.x; r1 += h.y; r2 += h.z; r3 += h.w;
  }
}

// ---------- scatter rows into code-grouped rowlist ----------
__global__ __launch_bounds__(256) void scatter_kernel(const float* __restrict__ out2q,
                                                      const unsigned short* __restrict__ blockhist,
                                                      unsigned short* __restrict__ rowlist){
  __shared__ int cur[1024];
  int tid = threadIdx.x, b = blockIdx.x;
  #pragma unroll
  for (int i = 0; i < 4; ++i) cur[tid + 256*i] = blockhist[b*1024 + tid + 256*i];
  __syncthreads();
  #pragma unroll
  for (int j = 0; j < 4; ++j){
    int row = b*1024 + tid + 256*j;
    int c = (int)out2q[row];
    int pos = atomicAdd(&cur[c], 1);
    rowlist[pos] = (unsigned short)row;
  }
}

// ---------- update: 1-wave blocks, 16 slots, 2-deep row prefetch ----------
__global__ __launch_bounds__(64) void update_kernel(
    f16* __restrict__ AH, f16* __restrict__ AL,
    const unsigned short* __restrict__ rowlist, const float* __restrict__ out2q,
    const float* __restrict__ codebooks, float* __restrict__ out4,
    float* __restrict__ rnorm, int q)
{
  const int lane = threadIdx.x;
  const int s0 = blockIdx.x * 16;
  int myrow = 0, mycode = 0;
  if (lane < 16){
    myrow = rowlist[s0 + lane];
    mycode = (int)out2q[myrow];
  }
  float vs[4] = {0.f, 0.f, 0.f, 0.f};
  float Wk[4] = {0.f, 0.f, 0.f, 0.f};
  int prev = -1;
  // prefetch slot 0
  int rowp = __shfl(myrow, 0, 64);
  f16x4 ph = *(const f16x4*)(AH + (size_t)rowp*256 + lane*4);
  f16x4 pl = *(const f16x4*)(AL + (size_t)rowp*256 + lane*4);
  for (int s = 0; s < 16; ++s){
    int row  = __shfl(myrow, s, 64);
    int code = __shfl(mycode, s, 64);
    f16x4 h4 = ph, l4 = pl;
    if (s < 15){
      int rown = __shfl(myrow, s+1, 64);
      ph = *(const f16x4*)(AH + (size_t)rown*256 + lane*4);
      pl = *(const f16x4*)(AL + (size_t)rown*256 + lane*4);
    }
    if (code != prev){
      if (prev >= 0){
        float* dst = out4 + (((size_t)q << 10) + prev)*256 + lane*4;
        #pragma unroll
        for (int t = 0; t < 4; ++t) atomicAdd(dst + t, vs[t] * OMG_F);
      }
      float4 wv = *(const float4*)&codebooks[(((size_t)q << 10) + code)*256 + lane*4];
      Wk[0] = wv.x; Wk[1] = wv.y; Wk[2] = wv.z; Wk[3] = wv.w;
      vs[0] = vs[1] = vs[2] = vs[3] = 0.f;
      prev = code;
    }
    size_t base = (size_t)row * 256 + lane*4;
    f16x4 nh, nl;
    float p = 0.f;
    #pragma unroll
    for (int t = 0; t < 4; ++t){
      float rj = (float)h4[t] + (float)l4[t] * LO_INV;
      vs[t] += rj;
      float rn_ = rj - Wk[t];
      f16 hh = (f16)rn_;
      nh[t] = hh;
      nl[t] = (f16)((rn_ - (float)hh) * LO_SCALE);
      p += rn_ * rn_;
    }
    *(f16x4*)(AH + base) = nh;
    *(f16x4*)(AL + base) = nl;
    #pragma unroll
    for (int o = 32; o > 0; o >>= 1) p += __shfl_down(p, o, 64);
    if (lane == 0) rnorm[row] = p;
  }
  if (prev >= 0){
    float* dst = out4 + (((size_t)q << 10) + prev)*256 + lane*4;
    #pragma unroll
    for (int t = 0; t < 4; ++t) atomicAdd(dst + t, vs[t] * OMG_F);
  }
}

// ---------- epilogue: logits = data - resid, loss ----------
__global__ __launch_bounds__(256) void logits_loss_kernel(
    const float* __restrict__ data, const f16* __restrict__ AH, const f16* __restrict__ AL,
    float* __restrict__ out0, float* __restrict__ out1)
{
  __shared__ float rs[32][257];
  int blk = blockIdx.x, b = blk >> 6, s0 = (blk & 63) * 32;
  int tid = threadIdx.x;
  int r0 = blk*32;
  int c2 = tid >> 3, k0 = (tid & 7) * 32;
  #pragma unroll
  for (int jc = 0; jc < 4; ++jc){
    size_t off = (size_t)(r0 + c2) * 256 + k0 + jc*8;
    f16x8 h8 = *(const f16x8*)(AH + off);
    f16x8 l8 = *(const f16x8*)(AL + off);
    #pragma unroll
    for (int j = 0; j < 8; ++j)
      rs[c2][k0 + jc*8 + j] = (float)h8[j] + (float)l8[j] * LO_INV;
  }
  __syncthreads();
  int c = tid & 31, g = tid >> 5;
  const float* dptr = data + (size_t)b * 524288 + s0;
  float* optr = out0 + (size_t)b * 524288 + s0;
  float lsum = 0.f;
  #pragma unroll 8
  for (int dd = 0; dd < 32; ++dd){
    int d = g*32 + dd;
    float r = rs[c][d];
    lsum += r*r;
    optr[(size_t)d * 2048 + c] = dptr[(size_t)d * 2048 + c] - r;
  }
  #pragma unroll
  for (int o = 32; o > 0; o >>= 1) lsum += __shfl_down(lsum, o, 64);
  if ((tid & 63) == 0) atomicAdd(out1, lsum * (1.0f / 8388608.0f));
}

// ---------- final: new_W = new_m / clip(new_N) ----------
__global__ __launch_bounds__(256) void out5_kernel(const float* __restrict__ out4,
                                                   const float* __restrict__ out3,
                                                   float* __restrict__ out5){
  int e4 = blockIdx.x*256 + threadIdx.x;
  float Nn = fmaxf(out3[e4 >> 6], 1e-8f);
  float4 v = ((const float4*)out4)[e4];
  v.x /= Nn; v.y /= Nn; v.z /= Nn; v.w /= Nn;
  ((float4*)out5)[e4] = v;
}

extern "C" void kernel_launch(void* const* d_in, const int* in_sizes, int n_in,
                              void* d_out, int out_size, void* d_ws, size_t ws_size,
                              hipStream_t stream){
  float* out = (float*)d_out;

  // size-keyed input binding
  const float* data = nullptr; const float* codebooks = nullptr;
  const float* Ni = nullptr;   const float* mi = nullptr;
  for (int i = 0; i < n_in; ++i){
    if      (in_sizes[i] == 8388608) data = (const float*)d_in[i];
    else if (in_sizes[i] == 8192)    Ni   = (const float*)d_in[i];
    else if (in_sizes[i] == 2097152){
      if (!codebooks) codebooks = (const float*)d_in[i];
      else            mi        = (const float*)d_in[i];
    }
  }
  if (!data || !codebooks || !Ni || !mi){
    sentinel_kernel<<<1, 64, 0, stream>>>(out, 6666.0f);
    return;
  }

  // ws layout (bytes):
  // AH 16,777,216 | AL 16,777,216 | whl 8,388,608 | wnorm 32,768 | rnorm 131,072 |
  // blockhist 65,536 | rowlist 65,536 | pv 524,288 | pi 262,144  = 43,122,688
  const size_t ws_need = 43122688ull;
  if (ws_size < ws_need){
    sentinel_kernel<<<1, 64, 0, stream>>>(out, 7777.0f);
    return;
  }
  f16*   AH     = (f16*)d_ws;
  f16*   AL     = AH + 8388608;
  f16*   whl    = AL + 8388608;
  float* wnormb = (float*)(whl + 4194304);
  float* rnorm  = wnormb + 8192;
  unsigned short* blockhist = (unsigned short*)(rnorm + 32768);
  unsigned short* rowlist   = blockhist + 32768;
  float* pv     = (float*)(rowlist + 32768);
  unsigned short* pi = (unsigned short*)(pv + 131072);

  // out offsets (fp32, reference return order)
  float* out0 = out;                  // logits  8388608
  float* out1 = out0 + 8388608;       // loss    1
  float* out2 = out1 + 1;             // indices 262144
  float* out3 = out2 + 262144;        // new_N   8192
  float* out4 = out3 + 8192;          // new_m   2097152
  float* out5 = out4 + 2097152;       // new_W   2097152

  hipMemsetAsync(out1, 0, sizeof(float), stream);

  wsplit_kernel<<<dim3(4096), 64, 0, stream>>>(codebooks, whl);
  rownorm_kernel<<<dim3(8192), 64, 0, stream>>>(codebooks, wnormb, 8192);
  init_kernel<<<dim3(1024), 256, 0, stream>>>(data, AH, AL, rnorm);
  out4init_kernel<<<dim3(2048), 256, 0, stream>>>(mi, out4);

  for (int q = 0; q < 8; ++q){
    float* out2q = out2 + (size_t)q * 32768;
    dist_kernel<<<dim3(256, 4), 256, 0, stream>>>(AH, AL, whl, wnormb, rnorm, pv, pi, q);
    combine_kernel<<<dim3(32), 256, 0, stream>>>(pv, pi, out2q, blockhist);
    scan_kernel<<<dim3(1), 256, 0, stream>>>(blockhist, Ni, out3, q);
    scatter_kernel<<<dim3(32), 256, 0, stream>>>(out2q, blockhist, rowlist);
    update_kernel<<<dim3(2048), 64, 0, stream>>>(AH, AL, rowlist, out2q,
                                                 codebooks, out4, rnorm, q);
  }

  logits_loss_kernel<<<dim3(1024), 256, 0, stream>>>(data, AH, AL, out0, out1);
  out5_kernel<<<dim3(2048), 256, 0, stream>>>(out4, out3, out5);
}

// Round 10
// 904.706 us; speedup vs baseline: 1.1296x; 1.1296x over previous
//
#include <hip/hip_runtime.h>
#include <hip/hip_bf16.h>

// RQV residual VQ — MFMA dist (32-code its, u64 atomicMin argmin) + fused scan/scatter.
// Inputs (fp32): data [16,256,2048], codebooks [8,1024,256], N_i [8,1024], m_i [8,1024,256]
// Outputs (fp32 concat): logits, loss, indices, new_N, new_m, new_W
// ws: AH/AL 2x16.78MB | whl 8.39MB | wnorm | rnorm | blockhist | rowlist | keybuf = 42,500,096 B

using f16   = _Float16;
using f16x4 = __attribute__((ext_vector_type(4))) _Float16;
using f16x8 = __attribute__((ext_vector_type(8))) _Float16;
using f32x4 = __attribute__((ext_vector_type(4))) float;
typedef unsigned long long u64;

#define GAMMA_F 0.99f
#define OMG_F   0.01f
#define LO_SCALE 1024.0f
#define LO_INV   (1.0f/1024.0f)

__global__ void sentinel_kernel(float* out, float v){
  if (threadIdx.x == 0 && blockIdx.x == 0) out[0] = v;
}

// ---------- codebook row norms ----------
__global__ __launch_bounds__(64) void rownorm_kernel(const float* __restrict__ X,
                                                     float* __restrict__ out, int rows){
  int r = blockIdx.x;
  if (r >= rows) return;
  int l = threadIdx.x;
  const float* x = X + (size_t)r * 256;
  float s = 0.f;
  #pragma unroll
  for (int i = 0; i < 4; i++){ float v = x[l + i*64]; s += v*v; }
  #pragma unroll
  for (int o = 32; o > 0; o >>= 1) s += __shfl_down(s, o, 64);
  if (l == 0) out[r] = s;
}

// ---------- codebook split into MFMA B-fragment order (verified) ----------
__global__ __launch_bounds__(64) void wsplit_kernel(const float* __restrict__ W,
                                                    f16* __restrict__ frag){
  int blk = blockIdx.x;                 // (q*64+ct)*8+kf
  int lane = threadIdx.x;
  int code = (blk >> 3 << 4) + (lane & 15);
  int k0   = (blk & 7)*32 + (lane >> 4)*8;
  const float* src = W + (size_t)code * 256 + k0;
  float4 a = *(const float4*)(src);
  float4 b = *(const float4*)(src + 4);
  float x[8] = {a.x,a.y,a.z,a.w, b.x,b.y,b.z,b.w};
  f16x8 h8, l8;
  #pragma unroll
  for (int i = 0; i < 8; i++){
    f16 h = (f16)x[i];
    h8[i] = h;
    l8[i] = (f16)((x[i] - (float)h) * LO_SCALE);
  }
  f16* dst = frag + (size_t)blk * 1024 + lane*8;
  *(f16x8*)dst         = h8;
  *(f16x8*)(dst + 512) = l8;
}

// ---------- init: data -> ROW-MAJOR fp16 hi/lo planes + rownorm ----------
__global__ __launch_bounds__(256) void init_kernel(const float* __restrict__ data,
                                                   f16* __restrict__ AH, f16* __restrict__ AL,
                                                   float* __restrict__ rnorm){
  __shared__ float rs[32][257];
  __shared__ float nrmp[32][8];
  int blk = blockIdx.x, b = blk >> 6, s0 = (blk & 63) * 32;
  int tid = threadIdx.x, c = tid & 31, g = tid >> 5;
  const float* dptr = data + (size_t)b * 524288 + s0;
  float np_ = 0.f;
  #pragma unroll 8
  for (int dd = 0; dd < 32; ++dd){
    int d = g*32 + dd;
    float x = dptr[(size_t)d * 2048 + c];
    rs[c][d] = x;
    np_ += x*x;
  }
  nrmp[c][g] = np_;
  __syncthreads();
  if (tid < 32){
    float s = 0.f;
    #pragma unroll
    for (int gg = 0; gg < 8; ++gg) s += nrmp[tid][gg];
    rnorm[blk*32 + tid] = s;
  }
  int r0 = blk*32;
  int c2 = tid >> 3, k0 = (tid & 7) * 32;
  #pragma unroll
  for (int jc = 0; jc < 4; ++jc){
    f16x8 h8, l8;
    #pragma unroll
    for (int j = 0; j < 8; ++j){
      float x = rs[c2][k0 + jc*8 + j];
      f16 h = (f16)x;
      h8[j] = h;
      l8[j] = (f16)((x - (float)h) * LO_SCALE);
    }
    size_t off = (size_t)(r0 + c2) * 256 + k0 + jc*8;
    *(f16x8*)(AH + off) = h8;
    *(f16x8*)(AL + off) = l8;
  }
}

// ---------- out4 = mi * gamma ----------
__global__ __launch_bounds__(256) void out4init_kernel(const float* __restrict__ mi,
                                                       float* __restrict__ out4){
  int e4 = blockIdx.x*256 + threadIdx.x;
  float4 v = ((const float4*)mi)[e4];
  v.x *= GAMMA_F; v.y *= GAMMA_F; v.z *= GAMMA_F; v.w *= GAMMA_F;
  ((float4*)out4)[e4] = v;
}

// ---------- dist: 32-code its, full B LDS dbuf, u64 atomicMin output ----------
__global__ __launch_bounds__(256, 2) void dist_kernel(
    const f16* __restrict__ AH, const f16* __restrict__ AL,
    const f16* __restrict__ whl, const float* __restrict__ wnorm,
    const float* __restrict__ rnorm, u64* __restrict__ keybuf, int q)
{
  __shared__ f16 Bs[2][16384];         // 32 codes x 256k x hi/lo per buffer (32KB)
  const int tid = threadIdx.x;
  const int lane = tid & 63;
  const int w = tid >> 6;
  const int rb = blockIdx.x, cs = blockIdx.y;
  const int rlo = lane & 15, kg = lane >> 4;
  const int T0 = rb*8 + w*2;

  // A fragments (32 rows, hi/lo) from row-major planes — coalesced
  f16x8 aH[2][8], aL[2][8];
  #pragma unroll
  for (int rt = 0; rt < 2; ++rt)
    #pragma unroll
    for (int kf = 0; kf < 8; ++kf){
      size_t off = (size_t)((T0+rt)*16 + rlo) * 256 + kf*32 + kg*8;
      aH[rt][kf] = *(const f16x8*)(AH + off);
      aL[rt][kf] = *(const f16x8*)(AL + off);
    }
  float rn[2][4];
  #pragma unroll
  for (int rt = 0; rt < 2; ++rt)
    #pragma unroll
    for (int i = 0; i < 4; ++i)
      rn[rt][i] = rnorm[(T0+rt)*16 + kg*4 + i];

  const f16* wb = whl + (size_t)q * 524288;
  const float* wn = wnorm + (q << 10);
  const int ct0 = cs * 16;             // 16 ct (= 256 codes) per cs, 2 ct per it

  float bestv[8]; int besti[8];
  #pragma unroll
  for (int r8_ = 0; r8_ < 8; ++r8_){ bestv[r8_] = 3.4e38f; besti[r8_] = 0; }

  // prologue: stage it=0 tile (32KB = 8 x f16x8 per thread)
  {
    const f16* src = wb + (size_t)ct0 * 8192;
    f16x8 st[8];
    #pragma unroll
    for (int j = 0; j < 8; ++j) st[j] = *(const f16x8*)(src + tid*8 + j*2048);
    #pragma unroll
    for (int j = 0; j < 8; ++j) *(f16x8*)(&Bs[0][0] + tid*8 + j*2048) = st[j];
  }

  for (int it = 0; it < 8; ++it){
    int cb = ct0 + it*2;
    __syncthreads();
    f16x8 nx[8];
    if (it < 7){
      const f16* src = wb + (size_t)(cb+2) * 8192;
      #pragma unroll
      for (int j = 0; j < 8; ++j) nx[j] = *(const f16x8*)(src + tid*8 + j*2048);
    }
    #pragma unroll
    for (int sub = 0; sub < 2; ++sub){
      const f16* bb = &Bs[it & 1][0] + sub*8192;
      f32x4 hh[2], cr[2];
      #pragma unroll
      for (int rt = 0; rt < 2; ++rt){ hh[rt] = (f32x4)0.0f; cr[rt] = (f32x4)0.0f; }
      __builtin_amdgcn_s_setprio(1);
      #pragma unroll
      for (int kf = 0; kf < 8; ++kf){
        f16x8 bh = *(const f16x8*)(bb + kf*1024 + lane*8);
        f16x8 bl = *(const f16x8*)(bb + kf*1024 + 512 + lane*8);
        hh[0] = __builtin_amdgcn_mfma_f32_16x16x32_f16(aH[0][kf], bh, hh[0], 0,0,0);
        cr[0] = __builtin_amdgcn_mfma_f32_16x16x32_f16(aH[0][kf], bl, cr[0], 0,0,0);
        cr[0] = __builtin_amdgcn_mfma_f32_16x16x32_f16(aL[0][kf], bh, cr[0], 0,0,0);
        hh[1] = __builtin_amdgcn_mfma_f32_16x16x32_f16(aH[1][kf], bh, hh[1], 0,0,0);
        cr[1] = __builtin_amdgcn_mfma_f32_16x16x32_f16(aH[1][kf], bl, cr[1], 0,0,0);
        cr[1] = __builtin_amdgcn_mfma_f32_16x16x32_f16(aL[1][kf], bh, cr[1], 0,0,0);
      }
      __builtin_amdgcn_s_setprio(0);
      int code = ((cb + sub) << 4) + rlo;
      float wnc = wn[code];
      #pragma unroll
      for (int rt = 0; rt < 2; ++rt)
        #pragma unroll
        for (int i = 0; i < 4; ++i){
          float dot = hh[rt][i] + cr[rt][i] * LO_INV;
          float d2 = (rn[rt][i] + wnc) - 2.0f * dot;
          int r8_ = rt*4 + i;
          if (d2 < bestv[r8_] || (d2 == bestv[r8_] && code < besti[r8_])){
            bestv[r8_] = d2; besti[r8_] = code;
          }
        }
    }
    if (it < 7){
      #pragma unroll
      for (int j = 0; j < 8; ++j) *(f16x8*)(&Bs[(it+1) & 1][0] + tid*8 + j*2048) = nx[j];
    }
  }

  // reduce across the 16 code-lanes (first-min, lowest index)
  #pragma unroll
  for (int off = 1; off <= 8; off <<= 1){
    #pragma unroll
    for (int r8_ = 0; r8_ < 8; ++r8_){
      float ov = __shfl_xor(bestv[r8_], off, 16);
      int   oi = __shfl_xor(besti[r8_], off, 16);
      if (ov < bestv[r8_] || (ov == bestv[r8_] && oi < besti[r8_])){
        bestv[r8_] = ov; besti[r8_] = oi;
      }
    }
  }
  if (rlo == 0){
    #pragma unroll
    for (int r8_ = 0; r8_ < 8; ++r8_){
      int rt = r8_ >> 2, i = r8_ & 3;
      int grow = (T0 + rt)*16 + kg*4 + i;
      unsigned fb = __float_as_uint(bestv[r8_]);
      fb = (fb & 0x80000000u) ? ~fb : (fb | 0x80000000u);   // monotone sortable
      u64 key = ((u64)fb << 32) | (unsigned)besti[r8_];
      atomicMin(keybuf + grow, key);
    }
  }
}

// ---------- hist: extract codes from keys, per-block histogram, reset keybuf ----------
__global__ __launch_bounds__(256) void hist_kernel(u64* __restrict__ keybuf,
                                                   float* __restrict__ out2q,
                                                   unsigned short* __restrict__ blockhist){
  __shared__ int h[1024];
  int tid = threadIdx.x, b = blockIdx.x;
  #pragma unroll
  for (int i = 0; i < 4; ++i) h[tid + 256*i] = 0;
  __syncthreads();
  #pragma unroll
  for (int j = 0; j < 4; ++j){
    int row = b*1024 + tid + 256*j;
    u64 k = keybuf[row];
    keybuf[row] = ~0ull;               // reset for next stage
    int c = (int)(k & 0xFFFF);
    out2q[row] = (float)c;
    atomicAdd(&h[c], 1);
  }
  __syncthreads();
  #pragma unroll
  for (int i = 0; i < 4; ++i)
    blockhist[b*1024 + tid + 256*i] = (unsigned short)h[tid + 256*i];
}

// ---------- fused scan + scatter (32 blocks, redundant scan) + new_N ----------
__global__ __launch_bounds__(256) void scanscatter_kernel(
    const unsigned short* __restrict__ blockhist, const float* __restrict__ out2q,
    unsigned short* __restrict__ rowlist, const float* __restrict__ Ni,
    float* __restrict__ out3, int q)
{
  __shared__ int wtot[4];
  __shared__ int cur[1024];
  int tid = threadIdx.x, b = blockIdx.x, lane = tid & 63, w = tid >> 6;
  const ushort4* bh4 = (const ushort4*)blockhist;
  int tot[4] = {0,0,0,0}, pre[4] = {0,0,0,0};
  for (int bb = 0; bb < 32; ++bb){
    ushort4 h = bh4[bb*256 + tid];
    if (bb < b){ pre[0]+=h.x; pre[1]+=h.y; pre[2]+=h.z; pre[3]+=h.w; }
    tot[0]+=h.x; tot[1]+=h.y; tot[2]+=h.z; tot[3]+=h.w;
  }
  int s = tot[0]+tot[1]+tot[2]+tot[3];
  int v = s;
  #pragma unroll
  for (int d = 1; d < 64; d <<= 1){
    int o = __shfl_up(v, d, 64);
    if (lane >= d) v += o;
  }
  if (lane == 63) wtot[w] = v;
  __syncthreads();
  int woff = 0;
  #pragma unroll
  for (int ww = 0; ww < 4; ++ww) if (ww < w) woff += wtot[ww];
  int base = woff + v - s;             // global exclusive prefix for code 4*tid
  if (b == 0){
    const int qb = q << 10;
    out3[qb + 4*tid+0] = Ni[qb + 4*tid+0]*GAMMA_F + (float)tot[0]*OMG_F;
    out3[qb + 4*tid+1] = Ni[qb + 4*tid+1]*GAMMA_F + (float)tot[1]*OMG_F;
    out3[qb + 4*tid+2] = Ni[qb + 4*tid+2]*GAMMA_F + (float)tot[2]*OMG_F;
    out3[qb + 4*tid+3] = Ni[qb + 4*tid+3]*GAMMA_F + (float)tot[3]*OMG_F;
  }
  cur[4*tid+0] = base + pre[0];
  cur[4*tid+1] = base + tot[0] + pre[1];
  cur[4*tid+2] = base + tot[0]+tot[1] + pre[2];
  cur[4*tid+3] = base + tot[0]+tot[1]+tot[2] + pre[3];
  __syncthreads();
  #pragma unroll
  for (int j = 0; j < 4; ++j){
    int row = b*1024 + tid + 256*j;
    int c = (int)out2q[row];
    int pos = atomicAdd(&cur[c], 1);
    rowlist[pos] = (unsigned short)row;
  }
}

// ---------- update: 1-wave blocks, 16 slots, 2-deep row prefetch ----------
__global__ __launch_bounds__(64) void update_kernel(
    f16* __restrict__ AH, f16* __restrict__ AL,
    const unsigned short* __restrict__ rowlist, const float* __restrict__ out2q,
    const float* __restrict__ codebooks, float* __restrict__ out4,
    float* __restrict__ rnorm, int q)
{
  const int lane = threadIdx.x;
  const int s0 = blockIdx.x * 16;
  int myrow = 0, mycode = 0;
  if (lane < 16){
    myrow = rowlist[s0 + lane];
    mycode = (int)out2q[myrow];
  }
  float vs[4] = {0.f, 0.f, 0.f, 0.f};
  float Wk[4] = {0.f, 0.f, 0.f, 0.f};
  int prev = -1;
  int rowp = __shfl(myrow, 0, 64);
  f16x4 ph = *(const f16x4*)(AH + (size_t)rowp*256 + lane*4);
  f16x4 pl = *(const f16x4*)(AL + (size_t)rowp*256 + lane*4);
  for (int s = 0; s < 16; ++s){
    int row  = __shfl(myrow, s, 64);
    int code = __shfl(mycode, s, 64);
    f16x4 h4 = ph, l4 = pl;
    if (s < 15){
      int rown = __shfl(myrow, s+1, 64);
      ph = *(const f16x4*)(AH + (size_t)rown*256 + lane*4);
      pl = *(const f16x4*)(AL + (size_t)rown*256 + lane*4);
    }
    if (code != prev){
      if (prev >= 0){
        float* dst = out4 + (((size_t)q << 10) + prev)*256 + lane*4;
        #pragma unroll
        for (int t = 0; t < 4; ++t) atomicAdd(dst + t, vs[t] * OMG_F);
      }
      float4 wv = *(const float4*)&codebooks[(((size_t)q << 10) + code)*256 + lane*4];
      Wk[0] = wv.x; Wk[1] = wv.y; Wk[2] = wv.z; Wk[3] = wv.w;
      vs[0] = vs[1] = vs[2] = vs[3] = 0.f;
      prev = code;
    }
    size_t base = (size_t)row * 256 + lane*4;
    f16x4 nh, nl;
    float p = 0.f;
    #pragma unroll
    for (int t = 0; t < 4; ++t){
      float rj = (float)h4[t] + (float)l4[t] * LO_INV;
      vs[t] += rj;
      float rn_ = rj - Wk[t];
      f16 hh = (f16)rn_;
      nh[t] = hh;
      nl[t] = (f16)((rn_ - (float)hh) * LO_SCALE);
      p += rn_ * rn_;
    }
    *(f16x4*)(AH + base) = nh;
    *(f16x4*)(AL + base) = nl;
    #pragma unroll
    for (int o = 32; o > 0; o >>= 1) p += __shfl_down(p, o, 64);
    if (lane == 0) rnorm[row] = p;
  }
  if (prev >= 0){
    float* dst = out4 + (((size_t)q << 10) + prev)*256 + lane*4;
    #pragma unroll
    for (int t = 0; t < 4; ++t) atomicAdd(dst + t, vs[t] * OMG_F);
  }
}

// ---------- epilogue: logits = data - resid, loss ----------
__global__ __launch_bounds__(256) void logits_loss_kernel(
    const float* __restrict__ data, const f16* __restrict__ AH, const f16* __restrict__ AL,
    float* __restrict__ out0, float* __restrict__ out1)
{
  __shared__ float rs[32][257];
  int blk = blockIdx.x, b = blk >> 6, s0 = (blk & 63) * 32;
  int tid = threadIdx.x;
  int r0 = blk*32;
  int c2 = tid >> 3, k0 = (tid & 7) * 32;
  #pragma unroll
  for (int jc = 0; jc < 4; ++jc){
    size_t off = (size_t)(r0 + c2) * 256 + k0 + jc*8;
    f16x8 h8 = *(const f16x8*)(AH + off);
    f16x8 l8 = *(const f16x8*)(AL + off);
    #pragma unroll
    for (int j = 0; j < 8; ++j)
      rs[c2][k0 + jc*8 + j] = (float)h8[j] + (float)l8[j] * LO_INV;
  }
  __syncthreads();
  int c = tid & 31, g = tid >> 5;
  const float* dptr = data + (size_t)b * 524288 + s0;
  float* optr = out0 + (size_t)b * 524288 + s0;
  float lsum = 0.f;
  #pragma unroll 8
  for (int dd = 0; dd < 32; ++dd){
    int d = g*32 + dd;
    float r = rs[c][d];
    lsum += r*r;
    optr[(size_t)d * 2048 + c] = dptr[(size_t)d * 2048 + c] - r;
  }
  #pragma unroll
  for (int o = 32; o > 0; o >>= 1) lsum += __shfl_down(lsum, o, 64);
  if ((tid & 63) == 0) atomicAdd(out1, lsum * (1.0f / 8388608.0f));
}

// ---------- final: new_W = new_m / clip(new_N) ----------
__global__ __launch_bounds__(256) void out5_kernel(const float* __restrict__ out4,
                                                   const float* __restrict__ out3,
                                                   float* __restrict__ out5){
  int e4 = blockIdx.x*256 + threadIdx.x;
  float Nn = fmaxf(out3[e4 >> 6], 1e-8f);
  float4 v = ((const float4*)out4)[e4];
  v.x /= Nn; v.y /= Nn; v.z /= Nn; v.w /= Nn;
  ((float4*)out5)[e4] = v;
}

extern "C" void kernel_launch(void* const* d_in, const int* in_sizes, int n_in,
                              void* d_out, int out_size, void* d_ws, size_t ws_size,
                              hipStream_t stream){
  float* out = (float*)d_out;

  // size-keyed input binding
  const float* data = nullptr; const float* codebooks = nullptr;
  const float* Ni = nullptr;   const float* mi = nullptr;
  for (int i = 0; i < n_in; ++i){
    if      (in_sizes[i] == 8388608) data = (const float*)d_in[i];
    else if (in_sizes[i] == 8192)    Ni   = (const float*)d_in[i];
    else if (in_sizes[i] == 2097152){
      if (!codebooks) codebooks = (const float*)d_in[i];
      else            mi        = (const float*)d_in[i];
    }
  }
  if (!data || !codebooks || !Ni || !mi){
    sentinel_kernel<<<1, 64, 0, stream>>>(out, 6666.0f);
    return;
  }

  // ws layout (bytes):
  // AH 16,777,216 | AL 16,777,216 | whl 8,388,608 | wnorm 32,768 | rnorm 131,072 |
  // blockhist 65,536 | rowlist 65,536 | keybuf 262,144 = 42,500,096
  const size_t ws_need = 42500096ull;
  if (ws_size < ws_need){
    sentinel_kernel<<<1, 64, 0, stream>>>(out, 7777.0f);
    return;
  }
  f16*   AH     = (f16*)d_ws;
  f16*   AL     = AH + 8388608;
  f16*   whl    = AL + 8388608;
  float* wnormb = (float*)(whl + 4194304);
  float* rnorm  = wnormb + 8192;
  unsigned short* blockhist = (unsigned short*)(rnorm + 32768);
  unsigned short* rowlist   = blockhist + 32768;
  u64*   keybuf = (u64*)(rowlist + 32768);

  // out offsets (fp32, reference return order)
  float* out0 = out;                  // logits  8388608
  float* out1 = out0 + 8388608;       // loss    1
  float* out2 = out1 + 1;             // indices 262144
  float* out3 = out2 + 262144;        // new_N   8192
  float* out4 = out3 + 8192;          // new_m   2097152
  float* out5 = out4 + 2097152;       // new_W   2097152

  hipMemsetAsync(out1, 0, sizeof(float), stream);
  hipMemsetAsync(keybuf, 0xFF, 262144, stream);

  wsplit_kernel<<<dim3(4096), 64, 0, stream>>>(codebooks, whl);
  rownorm_kernel<<<dim3(8192), 64, 0, stream>>>(codebooks, wnormb, 8192);
  init_kernel<<<dim3(1024), 256, 0, stream>>>(data, AH, AL, rnorm);
  out4init_kernel<<<dim3(2048), 256, 0, stream>>>(mi, out4);

  for (int q = 0; q < 8; ++q){
    float* out2q = out2 + (size_t)q * 32768;
    dist_kernel<<<dim3(256, 4), 256, 0, stream>>>(AH, AL, whl, wnormb, rnorm, keybuf, q);
    hist_kernel<<<dim3(32), 256, 0, stream>>>(keybuf, out2q, blockhist);
    scanscatter_kernel<<<dim3(32), 256, 0, stream>>>(blockhist, out2q, rowlist,
                                                     Ni, out3, q);
    update_kernel<<<dim3(2048), 64, 0, stream>>>(AH, AL, rowlist, out2q,
                                                 codebooks, out4, rnorm, q);
  }

  logits_loss_kernel<<<dim3(1024), 256, 0, stream>>>(data, AH, AL, out0, out1);
  out5_kernel<<<dim3(2048), 256, 0, stream>>>(out4, out3, out5);
}